// Round 15
// baseline (256.274 us; speedup 1.0000x reference)
//
#include <hip/hip_runtime.h>
#include <hip/hip_bf16.h>

typedef __hip_bfloat16 bf16;
typedef __attribute__((ext_vector_type(8))) short bf16x8s;
typedef __attribute__((ext_vector_type(4))) float f32x4;
typedef __attribute__((ext_vector_type(4))) int i32x4;

#define NB 64
#define NS 32
#define NV 10000
#define NE 512
#define NH 512
#define NF 2048
#define ND 1024

static __device__ __forceinline__ float bf2f(bf16 x) { return __bfloat162float(x); }
static __device__ __forceinline__ bf16 f2bf(float x) { return __float2bfloat16(x); }
static __device__ __forceinline__ short bfbits(float x) { bf16 h = f2bf(x); return *(short*)&h; }
static __device__ __forceinline__ f32x4 mfma16(bf16x8s a, bf16x8s b, f32x4 c) {
  return __builtin_amdgcn_mfma_f32_16x16x32_bf16(a, b, c, 0, 0, 0);
}

// ---- LLC-coherent (cross-XCD) accesses, bypassing per-XCD L1/L2 via sc0 sc1.
// Compiler does NOT track vmcnt — MUST wait_vm0() (waitcnt + sched_barrier,
// rule #18) before ANY use of results, including register-only VALU use.
static __device__ __forceinline__ i32x4 ld16_sc(const void* p) {
  i32x4 r;
  asm volatile("global_load_dwordx4 %0, %1, off sc0 sc1" : "=v"(r) : "v"(p) : "memory");
  return r;
}
static __device__ __forceinline__ float lddw_sc(const void* p) {
  float r;
  asm volatile("global_load_dword %0, %1, off sc0 sc1" : "=v"(r) : "v"(p) : "memory");
  return r;
}
static __device__ __forceinline__ void st16_sc(void* p, i32x4 v) {
  asm volatile("global_store_dwordx4 %0, %1, off sc0 sc1" :: "v"(p), "v"(v) : "memory");
}
static __device__ __forceinline__ void stud_sc(void* p, unsigned v) {
  asm volatile("global_store_dword %0, %1, off sc0 sc1" :: "v"(p), "v"(v) : "memory");
}
static __device__ __forceinline__ void stus_sc(void* p, unsigned v) {
  asm volatile("global_store_short %0, %1, off sc0 sc1" :: "v"(p), "v"(v) : "memory");
}
static __device__ __forceinline__ void wait_vm0() {
  asm volatile("s_waitcnt vmcnt(0)" ::: "memory");
  __builtin_amdgcn_sched_barrier(0);
}
static __device__ __forceinline__ unsigned min4u(i32x4 a) {
  return min(min((unsigned)a[0], (unsigned)a[1]), min((unsigned)a[2], (unsigned)a[3]));
}

// ================== THE kernel: everything persistent, zero setup ==================
// 256 WGs x 512 thr, 1 WG/CU. WGs 0..63: recurrence (R12/R14 proven protocol);
//   weights gathered in-prologue from f32 w_r/w_u/w_h (transpose-free); layer-0
//   WGs also compute their h0 tile (cnn@w_in+b_in, K=2048, wave-pair split) and
//   publish h0f/h0b + f_h0 flags; both layers' rec WGs gate on f_h0.
// WGs 64..159: x-part workers (pre ring); l0 gathers emb inline; weights/bias
//   gathered from f32 sources in prologue.
// WGs 160..255: output-GEMM workers (48 col-groups x 2 batch-halves), unchanged.
// Flags (dwords): f_h (l*4+mt)*32 | f_rh 256+ | f_pre 512+ | f_h0 896+mt*8 |
//                 compact-l1 960+.
__global__ __launch_bounds__(512, 1)
void k_gru2(const float* __restrict__ w_r, const float* __restrict__ w_u,
            const float* __restrict__ w_h, const float* __restrict__ b_r,
            const float* __restrict__ b_u, const float* __restrict__ b_h,
            const float* __restrict__ cnn, const float* __restrict__ w_in,
            const float* __restrict__ b_in,
            const int* __restrict__ tokens, const float* __restrict__ emb,
            float* __restrict__ h0f, bf16* __restrict__ h0b,
            bf16* __restrict__ seq0, bf16* __restrict__ seq1,
            bf16* __restrict__ rh_all, float* __restrict__ pre,
            unsigned* __restrict__ flags, const float* __restrict__ w_out,
            const float* __restrict__ b_out, float* __restrict__ out) {
  __shared__ char lds[40960];
  const int tid = threadIdx.x;
  const int lane = tid & 63;
  const int wv = tid >> 6;
  const int cl = lane & 15, g4 = lane >> 4;
  const int bid = blockIdx.x;
  const int in0 = lane * 16;
  const int dsw = in0 ^ ((wv & 7) << 4);

  auto stage = [&](char* dst, const char* srcbase, int rstr) {
    i32x4 v0 = ld16_sc(srcbase + (size_t)wv * rstr + in0);
    i32x4 v1 = ld16_sc(srcbase + (size_t)(wv + 8) * rstr + in0);
    wait_vm0();
    *(i32x4*)(dst + wv * 1024 + dsw) = v0;
    *(i32x4*)(dst + (wv + 8) * 1024 + dsw) = v1;
  };
  auto afrag = [&](const char* panel, int kk) {
    return *(const bf16x8s*)(panel + cl * 1024 + ((kk * 64 + g4 * 16) ^ ((cl & 7) << 4)));
  };
  auto poll8 = [&](const unsigned* f, unsigned tgt) {
    if (tid == 0) {
      for (;;) {
        i32x4 a = ld16_sc(f);
        i32x4 b = ld16_sc(f + 4);
        wait_vm0();                                  // #18 before the min chain
        if (min(min4u(a), min4u(b)) >= tgt) break;
        __builtin_amdgcn_s_sleep(1);
      }
    }
    __syncthreads();
    __builtin_amdgcn_sched_barrier(0);
  };
  auto poll32 = [&](const unsigned* f, unsigned tgt) {
    if (tid == 0) {
      for (;;) {
        i32x4 a0 = ld16_sc(f),      a1 = ld16_sc(f + 4),  a2 = ld16_sc(f + 8),
              a3 = ld16_sc(f + 12), a4 = ld16_sc(f + 16), a5 = ld16_sc(f + 20),
              a6 = ld16_sc(f + 24), a7 = ld16_sc(f + 28);
        wait_vm0();                                  // #18
        unsigned mn = min(min(min(min4u(a0), min4u(a1)), min(min4u(a2), min4u(a3))),
                          min(min(min4u(a4), min4u(a5)), min(min4u(a6), min4u(a7))));
        if (mn >= tgt) break;
        __builtin_amdgcn_s_sleep(1);
      }
    }
    __syncthreads();
    __builtin_amdgcn_sched_barrier(0);
  };
  // gather one B-fragment (16 cols x 8 k) from an f32 [K][512]-strided matrix
  auto bfrag = [&](const float* base, int k0, int col) {
    bf16x8s o;
#pragma unroll
    for (int jj = 0; jj < 8; jj++) o[jj] = bfbits(base[(size_t)(k0 + jj) * 512 + col]);
    return o;
  };

  if (bid < 64) {
    // ================= recurrence =================
    const int l = bid >> 5, wg5 = bid & 31, mt = wg5 & 3, ng = wg5 >> 2;
    const bool is_u = (wv >= 4);
    const int wsub = wv & 3;
    const int c = (ng * 4 + wsub) * 16 + cl;
    char* hp = lds;
    char* rp = lds + 16384;
    float* ul = (float*)(lds + 32768);
    char* rout = lds + 36864;
    char* hout = lds + 38912;

    unsigned* f_h  = flags + (l * 4 + mt) * 32;
    unsigned* f_rh = flags + 256 + (l * 4 + mt) * 32;
    unsigned* f_pre = flags + 512 + (l * 4 + mt) * 32;
    unsigned* f_h0 = flags + 896 + mt * 8;

    bf16* seql = l ? seq1 : seq0;
    bf16* rh = rh_all + (size_t)l * 64 * 512;
    float* prel = pre + (size_t)l * 4 * 1536 * 64;

    // ---- prologue: gather recurrent weights from f32 (h-part rows 512..1023)
    const float* wsrcA = (is_u ? w_u : w_r) + (size_t)l * ND * NH;
    bf16x8s bwA[16];
#pragma unroll
    for (int kk = 0; kk < 16; kk++)
      bwA[kk] = bfrag(wsrcA, 512 + kk * 32 + g4 * 8, c);
    bf16x8s bwB[16];
    if (!is_u) {
      const float* wsrcB = w_h + (size_t)l * ND * NH;
#pragma unroll
      for (int kk = 0; kk < 16; kk++)
        bwB[kk] = bfrag(wsrcB, 512 + kk * 32 + g4 * 8, c);
    }

    // ---- prologue: layer-0 WGs compute their h0 tile (cnn@w_in+b_in)
    if (l == 0) {
      const int ct = wv & 3, kh = wv >> 2;           // col-tile, K-half
      const int col = ng * 64 + ct * 16 + cl;
      f32x4 acc = {0.f, 0.f, 0.f, 0.f};
      const float* arow = cnn + (size_t)(mt * 16 + cl) * NF + kh * 1024;
#pragma unroll 4
      for (int kk = 0; kk < 32; kk++) {
        f32x4 a0 = *(const f32x4*)(arow + kk * 32 + g4 * 8);
        f32x4 a1 = *(const f32x4*)(arow + kk * 32 + g4 * 8 + 4);
        bf16x8s af;
#pragma unroll
        for (int j = 0; j < 4; j++) { af[j] = bfbits(a0[j]); af[4 + j] = bfbits(a1[j]); }
        bf16x8s bf = bfrag(w_in, kh * 1024 + kk * 32 + g4 * 8, col);
        acc = mfma16(af, bf, acc);
      }
      float* red = (float*)(lds + 32768);            // 4KB partial-reduce buffer
      if (kh == 1) {
#pragma unroll
        for (int j = 0; j < 4; j++) red[(ct * 64 + lane) * 4 + j] = acc[j];
      }
      __syncthreads();
      if (kh == 0) {
        float bz = b_in[col];
#pragma unroll
        for (int j = 0; j < 4; j++) {
          float v = acc[j] + red[(ct * 64 + lane) * 4 + j] + bz;
          int row = mt * 16 + g4 * 4 + j;
          union { float f; unsigned u; } cv; cv.f = v;
          stud_sc(h0f + (size_t)row * NH + col, cv.u);
          bf16 hb_ = f2bf(v);
          stus_sc(h0b + (size_t)row * NH + col, *(unsigned short*)&hb_);
        }
      }
      wait_vm0();
      __syncthreads();
      if (tid == 0) stud_sc(f_h0 + ng, 1u);
    }
    // both layers: wait for this group's h0
    poll8(f_h0, 1u);
    float h_reg[4];
    if (!is_u) {
#pragma unroll
      for (int j = 0; j < 4; j++)
        h_reg[j] = lddw_sc(h0f + (size_t)(mt * 16 + g4 * 4 + j) * NH + c);
      wait_vm0();
    }
    const int colA = is_u ? 512 + c : c;

    for (int t = 0; t < NS; t++) {
      if (tid == 0) {  // combined poll: pre(t) AND (t>0) h(t-1)
        for (;;) {
          i32x4 p0 = ld16_sc(f_pre), p1 = ld16_sc(f_pre + 4), p2 = ld16_sc(f_pre + 8);
          i32x4 h0_, h1_;
          if (t) { h0_ = ld16_sc(f_h); h1_ = ld16_sc(f_h + 4); }
          wait_vm0();                                // #18
          unsigned mnp = min(min(min4u(p0), min4u(p1)), min4u(p2));
          bool ok = mnp >= (unsigned)(t + 1);
          if (t) ok = ok && (min(min4u(h0_), min4u(h1_)) >= (unsigned)t);
          if (ok) break;
          __builtin_amdgcn_s_sleep(1);
        }
      }
      __syncthreads();
      __builtin_amdgcn_sched_barrier(0);
      const int slot = t & 3;
      i32x4 pv1 = ld16_sc(prel + ((size_t)(slot * 1536 + colA) * 64 + mt * 16 + g4 * 4));
      i32x4 pv2 = {0, 0, 0, 0};
      if (!is_u)
        pv2 = ld16_sc(prel + ((size_t)(slot * 1536 + 1024 + c) * 64 + mt * 16 + g4 * 4));
      if (t == 0) stage(hp, (const char*)(h0b + (size_t)mt * 16 * NH), 1024);
      else        stage(hp, (const char*)seql + ((size_t)(mt * 16) * NS + (t - 1)) * 1024,
                        NS * 1024);
      __syncthreads();
      f32x4 pA = *(f32x4*)&pv1;
      f32x4 pB = *(f32x4*)&pv2;
      // phase 1
      {
        f32x4 acc = {0.f, 0.f, 0.f, 0.f};
#pragma unroll
        for (int kk = 0; kk < 16; kk++) acc = mfma16(afrag(hp, kk), bwA[kk], acc);
#pragma unroll
        for (int j = 0; j < 4; j++) {
          float gate = 1.f / (1.f + expf(-(acc[j] + pA[j])));
          if (is_u) {
            ul[(g4 * 4 + j) * 64 + wsub * 16 + cl] = gate;
          } else {
            bf16 o = f2bf(gate * h_reg[j]);
            *(unsigned short*)(rout + (g4 * 4 + j) * 128 + (wsub * 16 + cl) * 2)
              = *(unsigned short*)&o;
          }
        }
      }
      __syncthreads();
      { // publish rh
        if (tid < 128) {
          int row = tid >> 3, ch = tid & 7;
          i32x4 v = *(i32x4*)(rout + row * 128 + ch * 16);
          st16_sc((char*)rh + (((size_t)(mt * 16 + row)) * NH + ng * 64 + ch * 8) * 2, v);
        }
        wait_vm0();
        __syncthreads();
        if (tid == 0) stud_sc(f_rh + ng, (unsigned)(t + 1));
      }
      poll8(f_rh, (unsigned)(t + 1));
      stage(rp, (const char*)(rh + (size_t)mt * 16 * NH), 1024);
      __syncthreads();
      // phase 2
      if (!is_u) {
        f32x4 acc = {0.f, 0.f, 0.f, 0.f};
#pragma unroll
        for (int kk = 0; kk < 16; kk++) acc = mfma16(afrag(rp, kk), bwB[kk], acc);
#pragma unroll
        for (int j = 0; j < 4; j++) {
          float htil = tanhf(acc[j] + pB[j]);
          float u = ul[(g4 * 4 + j) * 64 + wsub * 16 + cl];
          float hnew = h_reg[j] * u + (1.f - u) * htil;
          h_reg[j] = hnew;
          bf16 hn = f2bf(hnew);
          *(unsigned short*)(hout + (g4 * 4 + j) * 128 + (wsub * 16 + cl) * 2)
            = *(unsigned short*)&hn;
        }
      }
      __syncthreads();
      { // publish h into seq[l]
        if (tid < 128) {
          int row = tid >> 3, ch = tid & 7;
          i32x4 v = *(i32x4*)(hout + row * 128 + ch * 16);
          st16_sc((char*)seql + (((size_t)(mt * 16 + row) * NS + t) * NH + ng * 64 + ch * 8) * 2, v);
        }
        wait_vm0();
        __syncthreads();
        if (tid == 0) {
          stud_sc(f_h + ng, (unsigned)(t + 1));
          if (l == 1) stud_sc(flags + 960 + mt * 8 + ng, (unsigned)(t + 1));
        }
      }
    }
  } else if (bid < 160) {
    // ================= x-part worker =================
    const int wb = bid - 64;
    const int l = wb / 48, w48 = wb % 48, gg = w48 & 3, cw = w48 >> 2;
    char* xpan = lds;
    const int col = cw * 128 + wv * 16 + cl;         // 0..1535
    float* prel = pre + (size_t)l * 4 * 1536 * 64;
    unsigned* f_h0g = flags + (0 * 4 + gg) * 32;
    unsigned* f_own = flags + (l * 4 + gg) * 32;
    unsigned* f_out = flags + 512 + (l * 4 + gg) * 32 + cw;

    // prologue: gather x-part weights (rows 0..511) + bias from f32 sources
    const float* wsrc = (col < 512 ? w_r : (col < 1024 ? w_u : w_h)) + (size_t)l * ND * NH;
    const int colw = col & 511;
    bf16x8s wxw[16];
#pragma unroll
    for (int kk = 0; kk < 16; kk++)
      wxw[kk] = bfrag(wsrc, kk * 32 + g4 * 8, colw);
    const float bz = (col < 512 ? b_r[l * 512 + colw]
                     : (col < 1024 ? b_u[l * 512 + colw] : b_h[l * 512 + colw]));

    for (int t = 0; t < NS; t++) {
      if (l == 1 || t >= 4) {
        if (tid == 0) {
          for (;;) {
            i32x4 a0 = {0,0,0,0}, a1 = {0,0,0,0}, b0 = {0,0,0,0}, b1 = {0,0,0,0};
            if (l == 1) { a0 = ld16_sc(f_h0g); a1 = ld16_sc(f_h0g + 4); }
            if (t >= 4) { b0 = ld16_sc(f_own); b1 = ld16_sc(f_own + 4); }
            wait_vm0();                              // #18
            bool ok = true;
            if (l == 1) ok = min(min4u(a0), min4u(a1)) >= (unsigned)(t + 1);
            if (t >= 4) ok = ok && (min(min4u(b0), min4u(b1)) >= (unsigned)(t - 3));
            if (ok) break;
            __builtin_amdgcn_s_sleep(1);
          }
        }
        __syncthreads();
        __builtin_amdgcn_sched_barrier(0);
      }
      if (l == 0) {
        // inline embedding gather+convert: slab row r -> emb[tokens[gg*16+r][t]]
#pragma unroll
        for (int rr = 0; rr < 2; rr++) {
          int r = wv + rr * 8;
          int tok = tokens[(gg * 16 + r) * NS + t];
          const float* ep = emb + (size_t)tok * NE + lane * 8;
          f32x4 v0 = *(const f32x4*)ep;
          f32x4 v1 = *(const f32x4*)(ep + 4);
          bf16x8s o;
#pragma unroll
          for (int j = 0; j < 4; j++) { o[j] = bfbits(v0[j]); o[4 + j] = bfbits(v1[j]); }
          *(i32x4*)(xpan + r * 1024 + dsw) = *(i32x4*)&o;
        }
      } else {
        stage(xpan, (const char*)seq0 + ((size_t)(gg * 16) * NS + t) * 1024, NS * 1024);
      }
      __syncthreads();
      f32x4 acc = {0.f, 0.f, 0.f, 0.f};
#pragma unroll
      for (int kk = 0; kk < 16; kk++) acc = mfma16(afrag(xpan, kk), wxw[kk], acc);
      {
        f32x4 o;
#pragma unroll
        for (int j = 0; j < 4; j++) o[j] = acc[j] + bz;
        st16_sc(prel + ((size_t)((t & 3) * 1536 + col) * 64 + gg * 16 + g4 * 4),
                *(i32x4*)&o);
      }
      wait_vm0();
      __syncthreads();
      if (tid == 0) stud_sc(f_out, (unsigned)(t + 1));
    }
  } else {
    // ================= output-GEMM worker =================
    const int oj = bid - 160;                        // 0..95
    const int bh = oj & 1, cg = oj >> 1;             // batch half, col-group 0..47
    char* aslab = lds;                               // 32KB seq1 half-slab
    const int colb0 = (cg * 16 + wv * 2) * 16 + cl;
    const int colb1 = colb0 + 16;
    bf16x8s bw0[16], bw1[16];
#pragma unroll
    for (int kk = 0; kk < 16; kk++) {
      bf16x8s f0, f1;
#pragma unroll
      for (int jj = 0; jj < 8; jj++) {
        int k = kk * 32 + g4 * 8 + jj;
        f0[jj] = (colb0 < NV) ? bfbits(w_out[(size_t)k * NV + colb0]) : (short)0;
        f1[jj] = (colb1 < NV) ? bfbits(w_out[(size_t)k * NV + colb1]) : (short)0;
      }
      bw0[kk] = f0; bw1[kk] = f1;
    }
    const float bz0 = (colb0 < NV) ? b_out[colb0] : 0.f;
    const float bz1 = (colb1 < NV) ? b_out[colb1] : 0.f;
    unsigned* f1f = flags + 960;

    for (int t = 0; t < NS; t++) {
      poll32(f1f, (unsigned)(t + 1));
      { // stage 32-row half-slab
        i32x4 vv[4];
        int rows[4], offs[4];
#pragma unroll
        for (int k4 = 0; k4 < 4; k4++) {
          int chunk = k4 * 512 + tid;
          rows[k4] = chunk >> 6;
          offs[k4] = (chunk & 63) * 16;
          vv[k4] = ld16_sc((const char*)seq1 +
                           ((size_t)(bh * 32 + rows[k4]) * NS + t) * 1024 + offs[k4]);
        }
        wait_vm0();
#pragma unroll
        for (int k4 = 0; k4 < 4; k4++)
          *(i32x4*)(aslab + rows[k4] * 1024 + (offs[k4] ^ ((rows[k4] & 7) << 4))) = vv[k4];
      }
      __syncthreads();
      f32x4 acc00 = {}, acc01 = {}, acc10 = {}, acc11 = {};
#pragma unroll
      for (int kk = 0; kk < 16; kk++) {
        int r0 = cl, r1 = 16 + cl;
        bf16x8s a0 = *(const bf16x8s*)(aslab + r0 * 1024 +
                                       ((kk * 64 + g4 * 16) ^ ((r0 & 7) << 4)));
        bf16x8s a1 = *(const bf16x8s*)(aslab + r1 * 1024 +
                                       ((kk * 64 + g4 * 16) ^ ((r1 & 7) << 4)));
        acc00 = mfma16(a0, bw0[kk], acc00);
        acc01 = mfma16(a0, bw1[kk], acc01);
        acc10 = mfma16(a1, bw0[kk], acc10);
        acc11 = mfma16(a1, bw1[kk], acc11);
      }
#pragma unroll
      for (int j = 0; j < 4; j++) {
        int b0r = bh * 32 + g4 * 4 + j;
        int b1r = b0r + 16;
        if (colb0 < NV) {
          out[((size_t)b0r * NS + t) * NV + colb0] = acc00[j] + bz0;
          out[((size_t)b1r * NS + t) * NV + colb0] = acc10[j] + bz0;
        }
        if (colb1 < NV) {
          out[((size_t)b0r * NS + t) * NV + colb1] = acc01[j] + bz1;
          out[((size_t)b1r * NS + t) * NV + colb1] = acc11[j] + bz1;
        }
      }
      __syncthreads();
    }
  }
}

extern "C" void kernel_launch(void* const* d_in, const int* in_sizes, int n_in,
                              void* d_out, int out_size, void* d_ws, size_t ws_size,
                              hipStream_t stream) {
  const int*   tokens = (const int*)d_in[0];
  const float* cnn    = (const float*)d_in[1];
  const float* emb    = (const float*)d_in[2];
  const float* w_in   = (const float*)d_in[3];
  const float* b_in   = (const float*)d_in[4];
  const float* w_r    = (const float*)d_in[5];
  const float* b_r    = (const float*)d_in[6];
  const float* w_u    = (const float*)d_in[7];
  const float* b_u    = (const float*)d_in[8];
  const float* w_h    = (const float*)d_in[9];
  const float* b_h    = (const float*)d_in[10];
  const float* w_out  = (const float*)d_in[11];
  const float* b_out  = (const float*)d_in[12];
  float* out = (float*)d_out;

  char* ws = (char*)d_ws;
  size_t off = 0;
  auto alloc = [&](size_t bytes) { char* p = ws + off; off += (bytes + 255) & ~(size_t)255; return p; };
  bf16*  seq0    = (bf16*) alloc((size_t)2048 * 512 * 2);
  bf16*  seq1    = (bf16*) alloc((size_t)2048 * 512 * 2);
  float* pre     = (float*)alloc((size_t)2 * 4 * 1536 * 64 * 4);   // [l][ring4][c][b]
  float* h0f     = (float*)alloc((size_t)64 * 512 * 4);
  bf16*  h0b     = (bf16*) alloc((size_t)64 * 512 * 2);
  bf16*  rh_all  = (bf16*) alloc((size_t)2 * 64 * 512 * 2);
  unsigned* flags = (unsigned*)alloc(4096);   // 1024 dwords
  (void)ws_size; (void)in_sizes; (void)n_in; (void)out_size;

  hipMemsetAsync(flags, 0, 4096, stream);

  k_gru2<<<256, 512, 0, stream>>>(w_r, w_u, w_h, b_r, b_u, b_h,
                                  cnn, w_in, b_in, tokens, emb,
                                  h0f, h0b, seq0, seq1, rh_all, pre, flags,
                                  w_out, b_out, out);
}

// Round 16
// 232.041 us; speedup vs baseline: 1.1044x; 1.1044x over previous
//
#include <hip/hip_runtime.h>
#include <hip/hip_bf16.h>

typedef __hip_bfloat16 bf16;
typedef __attribute__((ext_vector_type(8))) short bf16x8s;
typedef __attribute__((ext_vector_type(4))) float f32x4;
typedef __attribute__((ext_vector_type(4))) int i32x4;

#define NB 64
#define NS 32
#define NV 10000
#define NE 512
#define NH 512
#define NF 2048
#define ND 1024

static __device__ __forceinline__ float bf2f(bf16 x) { return __bfloat162float(x); }
static __device__ __forceinline__ bf16 f2bf(float x) { return __float2bfloat16(x); }
static __device__ __forceinline__ short bfbits(float x) { bf16 h = f2bf(x); return *(short*)&h; }
static __device__ __forceinline__ f32x4 mfma16(bf16x8s a, bf16x8s b, f32x4 c) {
  return __builtin_amdgcn_mfma_f32_16x16x32_bf16(a, b, c, 0, 0, 0);
}

// ---- LLC-coherent (cross-XCD) accesses, bypassing per-XCD L1/L2 via sc0 sc1.
// Compiler does NOT track vmcnt — MUST wait_vm0() (waitcnt + sched_barrier,
// rule #18) before ANY use of results, including register-only VALU use.
static __device__ __forceinline__ i32x4 ld16_sc(const void* p) {
  i32x4 r;
  asm volatile("global_load_dwordx4 %0, %1, off sc0 sc1" : "=v"(r) : "v"(p) : "memory");
  return r;
}
static __device__ __forceinline__ void st16_sc(void* p, i32x4 v) {
  asm volatile("global_store_dwordx4 %0, %1, off sc0 sc1" :: "v"(p), "v"(v) : "memory");
}
static __device__ __forceinline__ void stud_sc(void* p, unsigned v) {
  asm volatile("global_store_dword %0, %1, off sc0 sc1" :: "v"(p), "v"(v) : "memory");
}
static __device__ __forceinline__ void wait_vm0() {
  asm volatile("s_waitcnt vmcnt(0)" ::: "memory");
  __builtin_amdgcn_sched_barrier(0);
}
static __device__ __forceinline__ unsigned min4u(i32x4 a) {
  return min(min((unsigned)a[0], (unsigned)a[1]), min((unsigned)a[2], (unsigned)a[3]));
}

// One 16x16 output tile per wave (cached path, plain GEMMs).
__device__ __forceinline__ f32x4 wave_tile16(const bf16* A, const bf16* BT,
                                             int lda, int K, int m0, int n0) {
  int lane = threadIdx.x & 63;
  int r = lane & 15, g = lane >> 4;
  const bf16* ap = A + (size_t)(m0 + r) * lda + g * 8;
  const bf16* bp = BT + (size_t)(n0 + r) * K + g * 8;
  f32x4 acc = {0.f, 0.f, 0.f, 0.f};
#pragma unroll 4
  for (int k = 0; k < K; k += 32) {
    bf16x8s a = *(const bf16x8s*)(ap + k);
    bf16x8s b = *(const bf16x8s*)(bp + k);
    acc = mfma16(a, b, acc);
  }
  return acc;
}

// ---------------- merged setup: cvt + w_in transpose + 12x weight transposes + bias ----
// 4620 blocks x 256 thr, all parts independent -> run concurrently in one launch.
__global__ void k_setup(const float* __restrict__ cnn, bf16* __restrict__ cnn_b,
                        const float* __restrict__ w_in, bf16* __restrict__ w_in_T,
                        const float* __restrict__ w_r, const float* __restrict__ w_u,
                        const float* __restrict__ w_h, bf16* __restrict__ ruhT,
                        bf16* __restrict__ hhT, bf16* __restrict__ xT,
                        const float* __restrict__ br, const float* __restrict__ bu,
                        const float* __restrict__ bh, float* __restrict__ bias) {
  const int bid = blockIdx.x;
  if (bid < 512) {
    // ---- cvt: cnn f32 -> bf16 (131072 elems)
    int i = bid * 256 + threadIdx.x;
    cnn_b[i] = f2bf(cnn[i]);
    return;
  }
  if (bid < 4608) {
    // ---- transposes: one 32x32 tile each
    const float* src; bf16* dst; int n0, k0, N;
    if (bid < 1536) {                                // w_in [2048][512] -> [512][2048]
      int b = bid - 512;
      n0 = (b & 15) * 32; k0 = (b >> 4) * 32; N = NH;
      src = w_in; dst = w_in_T;
      // dst stride = 2048
      __shared__ float tile[32][33];
      int tx = threadIdx.x & 31, ty = threadIdx.x >> 5;
      for (int i = ty; i < 32; i += 8)
        tile[i][tx] = src[(size_t)(k0 + i) * N + n0 + tx];
      __syncthreads();
      for (int i = ty; i < 32; i += 8)
        dst[(size_t)(n0 + i) * NF + k0 + tx] = f2bf(tile[tx][i]);
      return;
    }
    // 12x [512][512] layer-weight transposes
    int b = bid - 1536;                              // 0..3071
    int z = b >> 8, xy = b & 255;
    int l = z / 6, q = z % 6;
    const float* srcs[6] = {
      w_r + (size_t)l * ND * NH + (size_t)512 * NH,
      w_u + (size_t)l * ND * NH + (size_t)512 * NH,
      w_h + (size_t)l * ND * NH + (size_t)512 * NH,
      w_r + (size_t)l * ND * NH,
      w_u + (size_t)l * ND * NH,
      w_h + (size_t)l * ND * NH };
    bf16* dsts[6] = {
      ruhT + (size_t)l * 1024 * 512,
      ruhT + (size_t)l * 1024 * 512 + 512 * 512,
      hhT  + (size_t)l * 512 * 512,
      xT   + (size_t)l * 1536 * 512,
      xT   + (size_t)l * 1536 * 512 + 512 * 512,
      xT   + (size_t)l * 1536 * 512 + 1024 * 512 };
    src = srcs[q]; dst = dsts[q];
    n0 = (xy & 15) * 32; k0 = (xy >> 4) * 32;
    __shared__ float tile[32][33];
    int tx = threadIdx.x & 31, ty = threadIdx.x >> 5;
    for (int i = ty; i < 32; i += 8)
      tile[i][tx] = src[(size_t)(k0 + i) * NH + n0 + tx];
    __syncthreads();
    for (int i = ty; i < 32; i += 8)
      dst[(size_t)(n0 + i) * NH + k0 + tx] = f2bf(tile[tx][i]);
    return;
  }
  // ---- bias concat: [2][1536] f32
  int i = (bid - 4608) * 256 + threadIdx.x;
  if (i < 3072) {
    int l = i / 1536, c = i % 1536;
    const float* s = (c < 512) ? (br + l * 512 + c)
                   : (c < 1024 ? (bu + l * 512 + (c - 512)) : (bh + l * 512 + (c - 1024)));
    bias[i] = *s;
  }
}

// ---------------- h0 = cnn @ w_in + b_in, dual-store f32 + bf16 ----------------
__global__ void k_gemm_h0(const bf16* __restrict__ A, const bf16* __restrict__ BT,
                          const float* __restrict__ bias,
                          float* __restrict__ h0f, bf16* __restrict__ h0b) {
  int wid = blockIdx.x * 4 + (threadIdx.x >> 6);
  int mt = wid & 3, nt = wid >> 2;
  f32x4 acc = wave_tile16(A, BT, NF, NF, mt * 16, nt * 16);
  int lane = threadIdx.x & 63;
  int cl = lane & 15, g = lane >> 4;
  int col = nt * 16 + cl;
  float bv = bias[col];
#pragma unroll
  for (int j = 0; j < 4; j++) {
    int row = mt * 16 + g * 4 + j;
    float v = acc[j] + bv;
    h0f[(size_t)row * NH + col] = v;
    h0b[(size_t)row * NH + col] = f2bf(v);
  }
}

// ---------------- fused persistent: 2-layer GRU + x-workers + OUT-workers ----------------
// (byte-identical to R14's proven k_gru2)
__global__ __launch_bounds__(512, 1)
void k_gru2(const bf16* __restrict__ w_ruh, const bf16* __restrict__ w_hh,
            const bf16* __restrict__ w_x, const float* __restrict__ bias3,
            const float* __restrict__ h0f, const bf16* __restrict__ h0b,
            const int* __restrict__ tokens, const float* __restrict__ emb,
            bf16* __restrict__ seq0, bf16* __restrict__ seq1,
            bf16* __restrict__ rh_all, float* __restrict__ pre,
            unsigned* __restrict__ flags, const float* __restrict__ w_out,
            const float* __restrict__ b_out, float* __restrict__ out) {
  __shared__ char lds[40960];
  const int tid = threadIdx.x;
  const int lane = tid & 63;
  const int wv = tid >> 6;
  const int cl = lane & 15, g4 = lane >> 4;
  const int bid = blockIdx.x;
  const int in0 = lane * 16;
  const int dsw = in0 ^ ((wv & 7) << 4);

  auto stage = [&](char* dst, const char* srcbase, int rstr) {
    i32x4 v0 = ld16_sc(srcbase + (size_t)wv * rstr + in0);
    i32x4 v1 = ld16_sc(srcbase + (size_t)(wv + 8) * rstr + in0);
    wait_vm0();
    *(i32x4*)(dst + wv * 1024 + dsw) = v0;
    *(i32x4*)(dst + (wv + 8) * 1024 + dsw) = v1;
  };
  auto afrag = [&](const char* panel, int kk) {
    return *(const bf16x8s*)(panel + cl * 1024 + ((kk * 64 + g4 * 16) ^ ((cl & 7) << 4)));
  };
  auto poll8 = [&](const unsigned* f, unsigned tgt) {
    if (tid == 0) {
      for (;;) {
        i32x4 a = ld16_sc(f);
        i32x4 b = ld16_sc(f + 4);
        wait_vm0();                                  // #18 before the min chain
        if (min(min4u(a), min4u(b)) >= tgt) break;
        __builtin_amdgcn_s_sleep(1);
      }
    }
    __syncthreads();
    __builtin_amdgcn_sched_barrier(0);
  };
  auto poll32 = [&](const unsigned* f, unsigned tgt) {
    if (tid == 0) {
      for (;;) {
        i32x4 a0 = ld16_sc(f),      a1 = ld16_sc(f + 4),  a2 = ld16_sc(f + 8),
              a3 = ld16_sc(f + 12), a4 = ld16_sc(f + 16), a5 = ld16_sc(f + 20),
              a6 = ld16_sc(f + 24), a7 = ld16_sc(f + 28);
        wait_vm0();                                  // #18
        unsigned mn = min(min(min(min4u(a0), min4u(a1)), min(min4u(a2), min4u(a3))),
                          min(min(min4u(a4), min4u(a5)), min(min4u(a6), min4u(a7))));
        if (mn >= tgt) break;
        __builtin_amdgcn_s_sleep(1);
      }
    }
    __syncthreads();
    __builtin_amdgcn_sched_barrier(0);
  };

  if (bid < 64) {
    // ================= recurrence =================
    const int l = bid >> 5, wg5 = bid & 31, mt = wg5 & 3, ng = wg5 >> 2;
    const bool is_u = (wv >= 4);
    const int wsub = wv & 3;
    const int c = (ng * 4 + wsub) * 16 + cl;
    const int colA = is_u ? 512 + c : c;
    char* hp = lds;
    char* rp = lds + 16384;
    float* ul = (float*)(lds + 32768);
    char* rout = lds + 36864;
    char* hout = lds + 38912;

    unsigned* f_h  = flags + (l * 4 + mt) * 32;
    unsigned* f_rh = flags + 256 + (l * 4 + mt) * 32;
    unsigned* f_pre = flags + 512 + (l * 4 + mt) * 32;

    bf16* seql = l ? seq1 : seq0;
    bf16* rh = rh_all + (size_t)l * 64 * 512;
    float* prel = pre + (size_t)l * 4 * 1536 * 64;

    bf16x8s bwA[16];
    { const bf16* pa = w_ruh + (size_t)l * 1024 * 512 + (size_t)colA * NH + g4 * 8;
#pragma unroll
      for (int k = 0; k < 16; k++) bwA[k] = *(const bf16x8s*)(pa + k * 32); }
    bf16x8s bwB[16];
    float h_reg[4];
    if (!is_u) {
      const bf16* pb = w_hh + (size_t)l * 512 * 512 + (size_t)c * NH + g4 * 8;
#pragma unroll
      for (int k = 0; k < 16; k++) bwB[k] = *(const bf16x8s*)(pb + k * 32);
#pragma unroll
      for (int j = 0; j < 4; j++)
        h_reg[j] = h0f[(size_t)(mt * 16 + g4 * 4 + j) * NH + c];
    }

    for (int t = 0; t < NS; t++) {
      if (tid == 0) {  // combined poll: pre(t) AND (t>0) h(t-1)
        for (;;) {
          i32x4 p0 = ld16_sc(f_pre), p1 = ld16_sc(f_pre + 4), p2 = ld16_sc(f_pre + 8);
          i32x4 h0_, h1_;
          if (t) { h0_ = ld16_sc(f_h); h1_ = ld16_sc(f_h + 4); }
          wait_vm0();                                // #18
          unsigned mnp = min(min(min4u(p0), min4u(p1)), min4u(p2));
          bool ok = mnp >= (unsigned)(t + 1);
          if (t) ok = ok && (min(min4u(h0_), min4u(h1_)) >= (unsigned)t);
          if (ok) break;
          __builtin_amdgcn_s_sleep(1);
        }
      }
      __syncthreads();
      __builtin_amdgcn_sched_barrier(0);
      const int slot = t & 3;
      i32x4 pv1 = ld16_sc(prel + ((size_t)(slot * 1536 + colA) * 64 + mt * 16 + g4 * 4));
      i32x4 pv2 = {0, 0, 0, 0};
      if (!is_u)
        pv2 = ld16_sc(prel + ((size_t)(slot * 1536 + 1024 + c) * 64 + mt * 16 + g4 * 4));
      if (t == 0) stage(hp, (const char*)(h0b + (size_t)mt * 16 * NH), 1024);
      else        stage(hp, (const char*)seql + ((size_t)(mt * 16) * NS + (t - 1)) * 1024,
                        NS * 1024);
      __syncthreads();
      f32x4 pA = *(f32x4*)&pv1;
      f32x4 pB = *(f32x4*)&pv2;
      // phase 1
      {
        f32x4 acc = {0.f, 0.f, 0.f, 0.f};
#pragma unroll
        for (int kk = 0; kk < 16; kk++) acc = mfma16(afrag(hp, kk), bwA[kk], acc);
#pragma unroll
        for (int j = 0; j < 4; j++) {
          float gate = 1.f / (1.f + expf(-(acc[j] + pA[j])));
          if (is_u) {
            ul[(g4 * 4 + j) * 64 + wsub * 16 + cl] = gate;
          } else {
            bf16 o = f2bf(gate * h_reg[j]);
            *(unsigned short*)(rout + (g4 * 4 + j) * 128 + (wsub * 16 + cl) * 2)
              = *(unsigned short*)&o;
          }
        }
      }
      __syncthreads();
      { // publish rh
        if (tid < 128) {
          int row = tid >> 3, ch = tid & 7;
          i32x4 v = *(i32x4*)(rout + row * 128 + ch * 16);
          st16_sc((char*)rh + (((size_t)(mt * 16 + row)) * NH + ng * 64 + ch * 8) * 2, v);
        }
        wait_vm0();
        __syncthreads();
        if (tid == 0) stud_sc(f_rh + ng, (unsigned)(t + 1));
      }
      poll8(f_rh, (unsigned)(t + 1));
      stage(rp, (const char*)(rh + (size_t)mt * 16 * NH), 1024);
      __syncthreads();
      // phase 2
      if (!is_u) {
        f32x4 acc = {0.f, 0.f, 0.f, 0.f};
#pragma unroll
        for (int kk = 0; kk < 16; kk++) acc = mfma16(afrag(rp, kk), bwB[kk], acc);
#pragma unroll
        for (int j = 0; j < 4; j++) {
          float htil = tanhf(acc[j] + pB[j]);
          float u = ul[(g4 * 4 + j) * 64 + wsub * 16 + cl];
          float hnew = h_reg[j] * u + (1.f - u) * htil;
          h_reg[j] = hnew;
          bf16 hn = f2bf(hnew);
          *(unsigned short*)(hout + (g4 * 4 + j) * 128 + (wsub * 16 + cl) * 2)
            = *(unsigned short*)&hn;
        }
      }
      __syncthreads();
      { // publish h into seq[l]
        if (tid < 128) {
          int row = tid >> 3, ch = tid & 7;
          i32x4 v = *(i32x4*)(hout + row * 128 + ch * 16);
          st16_sc((char*)seql + (((size_t)(mt * 16 + row) * NS + t) * NH + ng * 64 + ch * 8) * 2, v);
        }
        wait_vm0();
        __syncthreads();
        if (tid == 0) {
          stud_sc(f_h + ng, (unsigned)(t + 1));
          if (l == 1) stud_sc(flags + 960 + mt * 8 + ng, (unsigned)(t + 1));
        }
      }
    }
  } else if (bid < 160) {
    // ================= x-part worker =================
    const int wb = bid - 64;
    const int l = wb / 48, w48 = wb % 48, gg = w48 & 3, cw = w48 >> 2;
    char* xpan = lds;
    const int col = cw * 128 + wv * 16 + cl;
    float* prel = pre + (size_t)l * 4 * 1536 * 64;
    unsigned* f_h0g = flags + (0 * 4 + gg) * 32;
    unsigned* f_own = flags + (l * 4 + gg) * 32;
    unsigned* f_out = flags + 512 + (l * 4 + gg) * 32 + cw;

    bf16x8s wxw[16];
    { const bf16* pw = w_x + (size_t)l * 1536 * 512 + (size_t)col * 512 + g4 * 8;
#pragma unroll
      for (int kk = 0; kk < 16; kk++) wxw[kk] = *(const bf16x8s*)(pw + kk * 32); }
    const float bz = bias3[l * 1536 + col];

    for (int t = 0; t < NS; t++) {
      if (l == 1 || t >= 4) {
        if (tid == 0) {
          for (;;) {
            i32x4 a0 = {0,0,0,0}, a1 = {0,0,0,0}, b0 = {0,0,0,0}, b1 = {0,0,0,0};
            if (l == 1) { a0 = ld16_sc(f_h0g); a1 = ld16_sc(f_h0g + 4); }
            if (t >= 4) { b0 = ld16_sc(f_own); b1 = ld16_sc(f_own + 4); }
            wait_vm0();                              // #18
            bool ok = true;
            if (l == 1) ok = min(min4u(a0), min4u(a1)) >= (unsigned)(t + 1);
            if (t >= 4) ok = ok && (min(min4u(b0), min4u(b1)) >= (unsigned)(t - 3));
            if (ok) break;
            __builtin_amdgcn_s_sleep(1);
          }
        }
        __syncthreads();
        __builtin_amdgcn_sched_barrier(0);
      }
      if (l == 0) {
        // inline embedding gather+convert
#pragma unroll
        for (int rr = 0; rr < 2; rr++) {
          int r = wv + rr * 8;
          int tok = tokens[(gg * 16 + r) * NS + t];
          const float* ep = emb + (size_t)tok * NE + lane * 8;
          f32x4 v0 = *(const f32x4*)ep;
          f32x4 v1 = *(const f32x4*)(ep + 4);
          bf16x8s o;
#pragma unroll
          for (int j = 0; j < 4; j++) { o[j] = bfbits(v0[j]); o[4 + j] = bfbits(v1[j]); }
          *(i32x4*)(xpan + r * 1024 + dsw) = *(i32x4*)&o;
        }
      } else {
        stage(xpan, (const char*)seq0 + ((size_t)(gg * 16) * NS + t) * 1024, NS * 1024);
      }
      __syncthreads();
      f32x4 acc = {0.f, 0.f, 0.f, 0.f};
#pragma unroll
      for (int kk = 0; kk < 16; kk++) acc = mfma16(afrag(xpan, kk), wxw[kk], acc);
      {
        f32x4 o;
#pragma unroll
        for (int j = 0; j < 4; j++) o[j] = acc[j] + bz;
        st16_sc(prel + ((size_t)((t & 3) * 1536 + col) * 64 + gg * 16 + g4 * 4),
                *(i32x4*)&o);
      }
      wait_vm0();
      __syncthreads();
      if (tid == 0) stud_sc(f_out, (unsigned)(t + 1));
    }
  } else {
    // ================= output-GEMM worker =================
    const int oj = bid - 160;
    const int bh = oj & 1, cg = oj >> 1;
    char* aslab = lds;
    const int colb0 = (cg * 16 + wv * 2) * 16 + cl;
    const int colb1 = colb0 + 16;
    bf16x8s bw0[16], bw1[16];
#pragma unroll
    for (int kk = 0; kk < 16; kk++) {
      bf16x8s f0, f1;
#pragma unroll
      for (int jj = 0; jj < 8; jj++) {
        int k = kk * 32 + g4 * 8 + jj;
        f0[jj] = (colb0 < NV) ? bfbits(w_out[(size_t)k * NV + colb0]) : (short)0;
        f1[jj] = (colb1 < NV) ? bfbits(w_out[(size_t)k * NV + colb1]) : (short)0;
      }
      bw0[kk] = f0; bw1[kk] = f1;
    }
    const float bz0 = (colb0 < NV) ? b_out[colb0] : 0.f;
    const float bz1 = (colb1 < NV) ? b_out[colb1] : 0.f;
    unsigned* f1f = flags + 960;

    for (int t = 0; t < NS; t++) {
      poll32(f1f, (unsigned)(t + 1));
      { // stage 32-row half-slab
        i32x4 vv[4];
        int rows[4], offs[4];
#pragma unroll
        for (int k4 = 0; k4 < 4; k4++) {
          int chunk = k4 * 512 + tid;
          rows[k4] = chunk >> 6;
          offs[k4] = (chunk & 63) * 16;
          vv[k4] = ld16_sc((const char*)seq1 +
                           ((size_t)(bh * 32 + rows[k4]) * NS + t) * 1024 + offs[k4]);
        }
        wait_vm0();
#pragma unroll
        for (int k4 = 0; k4 < 4; k4++)
          *(i32x4*)(aslab + rows[k4] * 1024 + (offs[k4] ^ ((rows[k4] & 7) << 4))) = vv[k4];
      }
      __syncthreads();
      f32x4 acc00 = {}, acc01 = {}, acc10 = {}, acc11 = {};
#pragma unroll
      for (int kk = 0; kk < 16; kk++) {
        int r0 = cl, r1 = 16 + cl;
        bf16x8s a0 = *(const bf16x8s*)(aslab + r0 * 1024 +
                                       ((kk * 64 + g4 * 16) ^ ((r0 & 7) << 4)));
        bf16x8s a1 = *(const bf16x8s*)(aslab + r1 * 1024 +
                                       ((kk * 64 + g4 * 16) ^ ((r1 & 7) << 4)));
        acc00 = mfma16(a0, bw0[kk], acc00);
        acc01 = mfma16(a0, bw1[kk], acc01);
        acc10 = mfma16(a1, bw0[kk], acc10);
        acc11 = mfma16(a1, bw1[kk], acc11);
      }
#pragma unroll
      for (int j = 0; j < 4; j++) {
        int b0r = bh * 32 + g4 * 4 + j;
        int b1r = b0r + 16;
        if (colb0 < NV) {
          out[((size_t)b0r * NS + t) * NV + colb0] = acc00[j] + bz0;
          out[((size_t)b1r * NS + t) * NV + colb0] = acc10[j] + bz0;
        }
        if (colb1 < NV) {
          out[((size_t)b0r * NS + t) * NV + colb1] = acc01[j] + bz1;
          out[((size_t)b1r * NS + t) * NV + colb1] = acc11[j] + bz1;
        }
      }
      __syncthreads();
    }
  }
}

extern "C" void kernel_launch(void* const* d_in, const int* in_sizes, int n_in,
                              void* d_out, int out_size, void* d_ws, size_t ws_size,
                              hipStream_t stream) {
  const int*   tokens = (const int*)d_in[0];
  const float* cnn    = (const float*)d_in[1];
  const float* emb    = (const float*)d_in[2];
  const float* w_in   = (const float*)d_in[3];
  const float* b_in   = (const float*)d_in[4];
  const float* w_r    = (const float*)d_in[5];
  const float* b_r    = (const float*)d_in[6];
  const float* w_u    = (const float*)d_in[7];
  const float* b_u    = (const float*)d_in[8];
  const float* w_h    = (const float*)d_in[9];
  const float* b_h    = (const float*)d_in[10];
  const float* w_out  = (const float*)d_in[11];
  const float* b_out  = (const float*)d_in[12];
  float* out = (float*)d_out;

  char* ws = (char*)d_ws;
  size_t off = 0;
  auto alloc = [&](size_t bytes) { char* p = ws + off; off += (bytes + 255) & ~(size_t)255; return p; };
  bf16*  seq0    = (bf16*) alloc((size_t)2048 * 512 * 2);
  bf16*  seq1    = (bf16*) alloc((size_t)2048 * 512 * 2);
  float* pre     = (float*)alloc((size_t)2 * 4 * 1536 * 64 * 4);   // [l][ring4][c][b]
  float* h0f     = (float*)alloc((size_t)64 * 512 * 4);
  bf16*  h0b     = (bf16*) alloc((size_t)64 * 512 * 2);
  bf16*  rh_all  = (bf16*) alloc((size_t)2 * 64 * 512 * 2);
  float* bias3   = (float*)alloc((size_t)2 * 1536 * 4);
  bf16*  cnn_b   = (bf16*) alloc((size_t)64 * 2048 * 2);
  bf16*  w_in_T  = (bf16*) alloc((size_t)512 * 2048 * 2);
  bf16*  w_ruh_T = (bf16*) alloc((size_t)2 * 1024 * 512 * 2);
  bf16*  w_hh_T  = (bf16*) alloc((size_t)2 * 512 * 512 * 2);
  bf16*  w_x_T   = (bf16*) alloc((size_t)2 * 1536 * 512 * 2);
  unsigned* flags = (unsigned*)alloc(4096);   // 1024 dwords
  (void)ws_size; (void)in_sizes; (void)n_in; (void)out_size;

  hipMemsetAsync(flags, 0, 4096, stream);

  k_setup<<<4620, 256, 0, stream>>>(cnn, cnn_b, w_in, w_in_T, w_r, w_u, w_h,
                                    w_ruh_T, w_hh_T, w_x_T, b_r, b_u, b_h, bias3);
  k_gemm_h0<<<32, 256, 0, stream>>>(cnn_b, w_in_T, b_in, h0f, h0b);
  k_gru2<<<256, 512, 0, stream>>>(w_ruh_T, w_hh_T, w_x_T, bias3, h0f, h0b,
                                  tokens, emb, seq0, seq1, rh_all, pre, flags,
                                  w_out, b_out, out);
}